// Round 5
// baseline (580.946 us; speedup 1.0000x reference)
//
#include <hip/hip_runtime.h>

// LIF spiking-neuron forward.
// inputs: (B,C,H,W,T) = (8,64,32,32,100) f32, T innermost (stride 1).
// outputs: syn, mem, spike -- each (B,C,H,W,T) f32, concatenated flat in d_out.
//
// Per pixel, sequential over t:
//   out_t    = (mem - 1 > 0) ? 1 : 0          (uses mem BEFORE update)
//   mem_next = (BETA*mem + syn) * (1 - out)   (uses OLD syn)
//   syn_next = ALPHA*syn + x_t
//
// NUMERICS: f64 recurrence, mul-then-add separated by an asm value barrier
// (no FMA contraction), exact double constants. Passed round 3/4 with absmax
// 2.375 (threshold 2.74) -- FP path unchanged here.
//
// PERF history: r3 435us (2-tile, 7 barriers/chunk, 31% occ); r4 528us
// (1-tile, 8 barriers/chunk, 58% occ but +100MB L2 refetch and barrier
// vmcnt(0) convoy). r5 root-cause fix: WAVE-PRIVATE slabs, ZERO barriers.
//   * each wave owns 64 pixels + a 5.25KB LDS slab; CDNA waves are lockstep
//     and the per-wave DS pipe is in-order -> no __syncthreads needed ever.
//   * waves stream independently -> global-load latency of one wave hides
//     under other waves' work (no block-wide vmcnt(0) drains).
//   * nontemporal stores: outputs are write-once -> keep them out of L2 so
//     input straddle-lines (128B lines shared by consecutive 80B chunks)
//     survive until the next chunk -> kills the r4 over-fetch.

typedef float f32x4 __attribute__((ext_vector_type(4)));

constexpr int    T_TOT = 100;
constexpr int    TC    = 20;          // timesteps per chunk
constexpr int    NCH   = T_TOT / TC;  // 5 chunks
constexpr int    ROWP  = 21;          // padded row stride; gcd(21,32)=1 -> 2-way (free)
constexpr int    BLOCK = 256;
constexpr int    PPW   = 64;          // pixels per wave (= lanes)
constexpr int    PPB   = 256;
constexpr int    V4R   = TC / 4;      // float4 ops per lane per chunk = 5
constexpr double ALPHA = 0.95;        // exact Python double
constexpr double BETA  = 0.9;         // exact Python double

// round-to-nearest mul then add in f64, contraction-proof.
__device__ __forceinline__ double mul_add_rn64(double a, double b, double c) {
    double p = a * b;
    asm("" : "+v"(p));
    return p + c;
}

// Transposing store of the wave's slab to one output: LDS -> coalesced
// nontemporal float4 global stores. Wave-local: no barrier needed.
#define STORE_SLAB(OPTR)                                                          \
    do {                                                                          \
        _Pragma("unroll")                                                         \
        for (int k = 0; k < V4R; ++k) {                                           \
            const int idx = lane + k * 64;                                        \
            const int p   = idx / V4R;                                            \
            const int e   = idx - p * V4R;                                        \
            const float* s = &slab[p * ROWP + e * 4];                             \
            f32x4 v; v.x = s[0]; v.y = s[1]; v.z = s[2]; v.w = s[3];              \
            __builtin_nontemporal_store(v, reinterpret_cast<f32x4*>(              \
                (OPTR) + (size_t)(pix0 + p) * T_TOT + tbase + e * 4));            \
        }                                                                         \
    } while (0)

__global__ __launch_bounds__(BLOCK, 6)
void lif_fwd(const float* __restrict__ in,
             float* __restrict__ syn_o,
             float* __restrict__ mem_o,
             float* __restrict__ spk_o)
{
    __shared__ float tile[PPB * ROWP];          // 21504 B; 4 wave-private slabs

    const int tid  = threadIdx.x;
    const int lane = tid & 63;
    const int wv   = tid >> 6;
    float* slab    = &tile[wv * PPW * ROWP];    // this wave's 64 rows
    const int pix0 = blockIdx.x * PPB + wv * PPW;

    double syn = 0.0, mem = 0.0;   // f64 carry (matches round-3/4 passing arithmetic)
    float rm[TC];                  // mem chunk buffer (statically indexed -> VGPRs)

    for (int c = 0; c < NCH; ++c) {
        const int tbase = c * TC;

        // ---- load chunk: 64 pixels x TC floats, float4-coalesced, into slab ----
        #pragma unroll
        for (int k = 0; k < V4R; ++k) {
            const int idx = lane + k * 64;
            const int p   = idx / V4R;
            const int e   = idx - p * V4R;
            const f32x4 v = *reinterpret_cast<const f32x4*>(
                in + (size_t)(pix0 + p) * T_TOT + tbase + e * 4);
            float* d = &slab[p * ROWP + e * 4];
            d[0] = v.x; d[1] = v.y; d[2] = v.z; d[3] = v.w;
        }
        // no barrier: slab is wave-private; DS pipe is in-order per wave

        // ---- recurrence (f64); syn overwrites x in row `lane` ----
        unsigned smask = 0u;
        {
            #pragma clang fp contract(off)
            #pragma unroll
            for (int j = 0; j < TC; ++j) {
                const double x     = (double)slab[lane * ROWP + j];
                const bool   o     = (mem - 1.0 > 0.0);
                const double om    = o ? 0.0 : 1.0;              // == (1.0 - out)
                const double mem_n = mul_add_rn64(BETA, mem, syn) * om;
                const double syn_n = mul_add_rn64(ALPHA, syn, x);
                slab[lane * ROWP + j] = (float)syn_n;            // in-place syn
                rm[j]  = (float)mem_n;
                smask |= (o ? 1u : 0u) << j;
                syn = syn_n; mem = mem_n;
            }
        }

        // ---- stream out syn, mem, spike through the same slab ----
        STORE_SLAB(syn_o);

        #pragma unroll
        for (int j = 0; j < TC; ++j) slab[lane * ROWP + j] = rm[j];
        STORE_SLAB(mem_o);

        #pragma unroll
        for (int j = 0; j < TC; ++j)
            slab[lane * ROWP + j] = ((smask >> j) & 1u) ? 1.0f : 0.0f;
        STORE_SLAB(spk_o);
    }
}

extern "C" void kernel_launch(void* const* d_in, const int* in_sizes, int n_in,
                              void* d_out, int out_size, void* d_ws, size_t ws_size,
                              hipStream_t stream) {
    const float* in = (const float*)d_in[0];
    float* out = (float*)d_out;

    const int n    = in_sizes[0];      // B*C*H*W*T = 52,428,800
    const int npix = n / T_TOT;        // 524,288

    float* syn_o = out;
    float* mem_o = out + (size_t)n;
    float* spk_o = out + 2 * (size_t)n;

    dim3 grid(npix / PPB);
    dim3 block(BLOCK);
    lif_fwd<<<grid, block, 0, stream>>>(in, syn_o, mem_o, spk_o);
}

// Round 6
// 579.102 us; speedup vs baseline: 1.0032x; 1.0032x over previous
//
#include <hip/hip_runtime.h>

// LIF spiking-neuron forward.
// inputs: (B,C,H,W,T) = (8,64,32,32,100) f32, T innermost (stride 1).
// outputs: syn, mem, spike -- each (B,C,H,W,T) f32, concatenated flat in d_out.
//
// Per pixel, sequential over t:
//   out_t    = (mem - 1 > 0) ? 1 : 0          (uses mem BEFORE update)
//   mem_next = (BETA*mem + syn) * (1 - out)   (uses OLD syn)
//   syn_next = ALPHA*syn + x_t
//
// NUMERICS: f64 recurrence, mul-then-add separated by an asm value barrier
// (no FMA contraction), exact double constants. Passed rounds 3-5 with absmax
// 2.375 (threshold 2.74) -- FP path is bit-identical here.
//
// PERF history:
//   r3 435us: block-LDS transpose, 35 barrier-drains, 3 blk/CU, FETCH 245MB
//   r4 528us: 6 blk/CU -> straddle lines evicted, FETCH 348MB
//   r5 581us: wave-private+nontemporal -> NT stores lose L2 write-combining
// r6 root-cause reset: NO LDS AT ALL. One thread per pixel, direct strided
// float4 I/O. Instruction-level coalescing is sacrificed, but LINE-level
// efficiency is preserved: each 128B line holds 8 float4 pieces of ONE pixel
// row, all accessed by the same lane within a ~8-instruction window (20-step
// register stash per chunk), so L1/L2 complete every line; chunk-boundary
// straddle lines are absorbed by the 256MB L3. Zero barriers, zero DS ops,
// ~28 waves/CU of pure TLP to hide HBM latency.

typedef float f32x4 __attribute__((ext_vector_type(4)));

constexpr int    T_TOT = 100;
constexpr int    TC    = 20;          // timesteps per register chunk
constexpr int    NCH   = T_TOT / TC;  // 5 chunks
constexpr int    V4    = TC / 4;      // float4s per chunk = 5
constexpr int    BLOCK = 256;
constexpr double ALPHA = 0.95;        // exact Python double
constexpr double BETA  = 0.9;         // exact Python double

// round-to-nearest mul then add in f64, contraction-proof: the empty asm
// makes the product opaque so the backend cannot form v_fma_f64 across it.
__device__ __forceinline__ double mul_add_rn64(double a, double b, double c) {
    double p = a * b;
    asm("" : "+v"(p));
    return p + c;
}

__global__ __launch_bounds__(BLOCK)
void lif_fwd(const float* __restrict__ in,
             float* __restrict__ syn_o,
             float* __restrict__ mem_o,
             float* __restrict__ spk_o)
{
    const size_t g = (size_t)blockIdx.x * BLOCK + threadIdx.x;  // pixel id
    const float* xp = in    + g * T_TOT;
    float*       sp = syn_o + g * T_TOT;
    float*       mp = mem_o + g * T_TOT;
    float*       kp = spk_o + g * T_TOT;

    double syn = 0.0, mem = 0.0;    // f64 carry (bit-identical to r3-r5 path)

    for (int c = 0; c < NCH; ++c) {
        const int tb = c * TC;

        // ---- load this chunk's 5 float4 up front (independent -> MLP) ----
        f32x4 xb[V4];
        #pragma unroll
        for (int e = 0; e < V4; ++e)
            xb[e] = *reinterpret_cast<const f32x4*>(xp + tb + e * 4);

        // ---- recurrence (f64), outputs stashed in registers ----
        float rs[TC], rm[TC];       // statically indexed (full unroll) -> VGPRs
        unsigned smask = 0u;
        {
            #pragma clang fp contract(off)
            #pragma unroll
            for (int j = 0; j < TC; ++j) {
                const double x     = (double)xb[j >> 2][j & 3];
                const bool   o     = (mem - 1.0 > 0.0);
                const double om    = o ? 0.0 : 1.0;              // == (1.0 - out)
                const double mem_n = mul_add_rn64(BETA, mem, syn) * om;
                const double syn_n = mul_add_rn64(ALPHA, syn, x);
                rs[j]  = (float)syn_n;
                rm[j]  = (float)mem_n;
                smask |= (o ? 1u : 0u) << j;
                syn = syn_n; mem = mem_n;
            }
        }

        // ---- burst stores, one output at a time (closes each 128B line's
        //      write window within a few instructions -> L2 merges) ----
        #pragma unroll
        for (int e = 0; e < V4; ++e) {
            f32x4 v;
            v.x = rs[4*e]; v.y = rs[4*e+1]; v.z = rs[4*e+2]; v.w = rs[4*e+3];
            *reinterpret_cast<f32x4*>(sp + tb + e * 4) = v;
        }
        #pragma unroll
        for (int e = 0; e < V4; ++e) {
            f32x4 v;
            v.x = rm[4*e]; v.y = rm[4*e+1]; v.z = rm[4*e+2]; v.w = rm[4*e+3];
            *reinterpret_cast<f32x4*>(mp + tb + e * 4) = v;
        }
        #pragma unroll
        for (int e = 0; e < V4; ++e) {
            f32x4 v;
            v.x = ((smask >> (4*e  )) & 1u) ? 1.0f : 0.0f;
            v.y = ((smask >> (4*e+1)) & 1u) ? 1.0f : 0.0f;
            v.z = ((smask >> (4*e+2)) & 1u) ? 1.0f : 0.0f;
            v.w = ((smask >> (4*e+3)) & 1u) ? 1.0f : 0.0f;
            *reinterpret_cast<f32x4*>(kp + tb + e * 4) = v;
        }
    }
}

extern "C" void kernel_launch(void* const* d_in, const int* in_sizes, int n_in,
                              void* d_out, int out_size, void* d_ws, size_t ws_size,
                              hipStream_t stream) {
    const float* in = (const float*)d_in[0];
    float* out = (float*)d_out;

    const int n    = in_sizes[0];      // B*C*H*W*T = 52,428,800
    const int npix = n / T_TOT;        // 524,288

    float* syn_o = out;
    float* mem_o = out + (size_t)n;
    float* spk_o = out + 2 * (size_t)n;

    dim3 grid(npix / BLOCK);           // 2048 blocks, no tail
    dim3 block(BLOCK);
    lif_fwd<<<grid, block, 0, stream>>>(in, syn_o, mem_o, spk_o);
}

// Round 7
// 425.311 us; speedup vs baseline: 1.3659x; 1.3616x over previous
//
#include <hip/hip_runtime.h>

// LIF spiking-neuron forward.
// inputs: (B,C,H,W,T) = (8,64,32,32,100) f32, T innermost (stride 1).
// outputs: syn, mem, spike -- each (B,C,H,W,T) f32, concatenated flat in d_out.
//
// Per pixel, sequential over t:
//   out_t    = (mem - 1 > 0) ? 1 : 0          (uses mem BEFORE update)
//   mem_next = (BETA*mem + syn) * (1 - out)   (uses OLD syn)
//   syn_next = ALPHA*syn + x_t
//
// NUMERICS: f64 recurrence, mul-then-add split by an asm value barrier (no
// FMA contraction), exact double constants. Passed r3-r6 with absmax 2.375
// (threshold 2.74) -- FP path bit-identical here.
//
// PERF history:
//   r3 435us: LDS transpose both ways, 7 barriers/chunk -> convoy, 2.3TB/s
//   r4 528us: 6 blk/CU -> straddle leak (FETCH +100MB), convoy remains
//   r5 581us: wave-private OK, but nontemporal stores lose L2 write-combining
//   r6 579us: register scatter stores -> WRITE 1.26GB (2x), write-allocate
// r7 = proven-good pieces only:
//   * input: register-direct float4 loads (r6-proven read path), double
//     buffered -- prefetch chunk c+1 issued BEFORE chunk c's compute (T14)
//   * outputs syn/mem: wave-private LDS slab transpose (r5-proven, no
//     barriers ever), REGULAR stores (L2 write-combines partial lines)
//   * spike: no LDS -- transpose the 20-bit spike mask via __shfl
//   * 4 blocks/CU (16 independent wave streams), ~100 VGPR, 28.7KB LDS

typedef float f32x4 __attribute__((ext_vector_type(4)));

constexpr int    T_TOT = 100;
constexpr int    TC    = 20;          // timesteps per chunk
constexpr int    NCH   = T_TOT / TC;  // 5 chunks
constexpr int    V4    = TC / 4;      // float4s per pixel-chunk = 5
constexpr int    ROWF  = 28;          // slab row stride (112B: 16B-aligned, banks spread over 8 rows)
constexpr int    BLOCK = 256;
constexpr int    PPW   = 64;          // pixels per wave
constexpr int    PPB   = 256;
constexpr double ALPHA = 0.95;        // exact Python double
constexpr double BETA  = 0.9;         // exact Python double

// round-to-nearest mul then add in f64, contraction-proof.
__device__ __forceinline__ double mul_add_rn64(double a, double b, double c) {
    double p = a * b;
    asm("" : "+v"(p));
    return p + c;
}

__global__ __launch_bounds__(BLOCK, 4)
void lif_fwd(const float* __restrict__ in,
             float* __restrict__ syn_o,
             float* __restrict__ mem_o,
             float* __restrict__ spk_o)
{
    __shared__ float tile[4 * PPW * ROWF];      // 28672 B; 4 wave-private slabs

    const int tid  = threadIdx.x;
    const int lane = tid & 63;
    const int wv   = tid >> 6;
    float* slab    = &tile[wv * PPW * ROWF];
    const int pix0 = blockIdx.x * PPB + wv * PPW;

    const float* xp = in + (size_t)(pix0 + lane) * T_TOT;   // this lane's row

    double syn = 0.0, mem = 0.0;       // f64 carry (bit-identical r3-r6 path)
    f32x4 xbuf[2][V4];                 // double-buffered input chunk

    // prefetch chunk 0
    #pragma unroll
    for (int e = 0; e < V4; ++e)
        xbuf[0][e] = *reinterpret_cast<const f32x4*>(xp + e * 4);

    #pragma unroll                      // full unroll: all xbuf indices static
    for (int c = 0; c < NCH; ++c) {
        const int tb = c * TC;

        // ---- issue prefetch of chunk c+1 before any compute (T14) ----
        if (c + 1 < NCH) {
            #pragma unroll
            for (int e = 0; e < V4; ++e)
                xbuf[(c + 1) & 1][e] = *reinterpret_cast<const f32x4*>(
                    xp + (c + 1) * TC + e * 4);
        }

        // ---- recurrence (f64), outputs to registers ----
        float rs[TC], rm[TC];
        unsigned smask = 0u;
        {
            #pragma clang fp contract(off)
            #pragma unroll
            for (int j = 0; j < TC; ++j) {
                const double x     = (double)xbuf[c & 1][j >> 2][j & 3];
                const bool   o     = (mem - 1.0 > 0.0);
                const double om    = o ? 0.0 : 1.0;              // == (1.0 - out)
                const double mem_n = mul_add_rn64(BETA, mem, syn) * om;
                const double syn_n = mul_add_rn64(ALPHA, syn, x);
                rs[j]  = (float)syn_n;
                rm[j]  = (float)mem_n;
                smask |= (o ? 1u : 0u) << j;
                syn = syn_n; mem = mem_n;
            }
        }

        // ---- syn: slab transpose (wave-private, in-order DS pipe, no barrier) ----
        #pragma unroll
        for (int e = 0; e < V4; ++e) {
            f32x4 v;
            v.x = rs[4*e]; v.y = rs[4*e+1]; v.z = rs[4*e+2]; v.w = rs[4*e+3];
            *reinterpret_cast<f32x4*>(&slab[lane * ROWF + 4 * e]) = v;
        }
        #pragma unroll
        for (int k = 0; k < V4; ++k) {
            const int idx = lane + 64 * k;
            const int p   = idx / 5;
            const int e   = idx - 5 * p;
            const f32x4 v = *reinterpret_cast<const f32x4*>(&slab[p * ROWF + 4 * e]);
            *reinterpret_cast<f32x4*>(
                syn_o + (size_t)(pix0 + p) * T_TOT + tb + 4 * e) = v;
        }

        // ---- mem: same slab, reused (in-order per wave) ----
        #pragma unroll
        for (int e = 0; e < V4; ++e) {
            f32x4 v;
            v.x = rm[4*e]; v.y = rm[4*e+1]; v.z = rm[4*e+2]; v.w = rm[4*e+3];
            *reinterpret_cast<f32x4*>(&slab[lane * ROWF + 4 * e]) = v;
        }
        #pragma unroll
        for (int k = 0; k < V4; ++k) {
            const int idx = lane + 64 * k;
            const int p   = idx / 5;
            const int e   = idx - 5 * p;
            const f32x4 v = *reinterpret_cast<const f32x4*>(&slab[p * ROWF + 4 * e]);
            *reinterpret_cast<f32x4*>(
                mem_o + (size_t)(pix0 + p) * T_TOT + tb + 4 * e) = v;
        }

        // ---- spike: transpose the bitmask via shuffle (no LDS) ----
        #pragma unroll
        for (int k = 0; k < V4; ++k) {
            const int idx = lane + 64 * k;
            const int p   = idx / 5;
            const int e   = idx - 5 * p;
            const unsigned m = (unsigned)__shfl((int)smask, p, 64);
            f32x4 v;
            v.x = ((m >> (4*e    )) & 1u) ? 1.0f : 0.0f;
            v.y = ((m >> (4*e + 1)) & 1u) ? 1.0f : 0.0f;
            v.z = ((m >> (4*e + 2)) & 1u) ? 1.0f : 0.0f;
            v.w = ((m >> (4*e + 3)) & 1u) ? 1.0f : 0.0f;
            *reinterpret_cast<f32x4*>(
                spk_o + (size_t)(pix0 + p) * T_TOT + tb + 4 * e) = v;
        }
    }
}

extern "C" void kernel_launch(void* const* d_in, const int* in_sizes, int n_in,
                              void* d_out, int out_size, void* d_ws, size_t ws_size,
                              hipStream_t stream) {
    const float* in = (const float*)d_in[0];
    float* out = (float*)d_out;

    const int n    = in_sizes[0];      // B*C*H*W*T = 52,428,800
    const int npix = n / T_TOT;        // 524,288

    float* syn_o = out;
    float* mem_o = out + (size_t)n;
    float* spk_o = out + 2 * (size_t)n;

    dim3 grid(npix / PPB);             // 2048 blocks
    dim3 block(BLOCK);
    lif_fwd<<<grid, block, 0, stream>>>(in, syn_o, mem_o, spk_o);
}